// Round 22
// baseline (446.687 us; speedup 1.0000x reference)
//
#include <hip/hip_runtime.h>
#include <stdint.h>

#define PN 24564
#define BN 64
#define MN 32
#define CN 81
#define MG 4       // gt boxes per block in k_gt_best
#define TR 64      // rows per tile (measured optimum)
#define BLK 256    // threads per WG (4 per row)
#define TPW 16     // tiles per workgroup (persistent)
#define WPB 24     // workgroups per batch (384 tiles / 16)
#define WGS (BN * WPB)   // 1536 persistent workgroups
#define NF4_FULL 1296    // f4 per full tile (64*81/4)

typedef float f4 __attribute__((ext_vector_type(4)));
typedef unsigned long long u64;
typedef unsigned int u32;

// ---------------- workspace layout ----------------
constexpr size_t SZ_BP4   = (size_t)BN * PN * 4;        // ce_neg
constexpr size_t OFF_PACK = SZ_BP4;                     // packed u64 [BN*MN]
constexpr size_t SZ_PACK  = (size_t)BN * MN * 8;
constexpr size_t OFF_PCNT = OFF_PACK + SZ_PACK;         // per-batch pos count (BN i32)
constexpr size_t OFF_NP   = OFF_PCNT + BN * 4;          // num_pos (4B) + 4B pad
constexpr size_t OFF_ACC  = OFF_NP + 8;                 // 3 doubles
constexpr size_t OFF_TICK = OFF_ACC + 24;               // ticket u32
constexpr size_t OFF_DONE = OFF_TICK + 4;               // done[BN] u32
constexpr size_t ZERO_OFF = OFF_PCNT;
constexpr size_t ZERO_WORDS = (BN * 4 + 8 + 24 + 4 + BN * 4) / 4;  // 137 words

__device__ __forceinline__ float sl1f(float d) {
  float ad = fabsf(d);
  return ad < 1.0f ? 0.5f * d * d : ad - 0.5f;
}

__device__ __forceinline__ u64 shfl_xor_u64w(u64 v, int m, int w) {
  u32 lo = (u32)v, hi = (u32)(v >> 32);
  lo = (u32)__shfl_xor((int)lo, m, w);
  hi = (u32)__shfl_xor((int)hi, m, w);
  return ((u64)hi << 32) | lo;
}

// ---------------- K1: per-gt best prior (argmax over p), 4 gt per block ----
// Block (0,0) also zeroes the accumulator tail + ticket + done counters
// (kernel boundary orders this before k_fused).
__global__ __launch_bounds__(256)
void k_gt_best(const f4* __restrict__ priors,
               const f4* __restrict__ gt_boxes,
               u64* __restrict__ packed_best,
               u32* __restrict__ zero_tail)
{
  const int b = blockIdx.y;
  const int mbase = blockIdx.x * MG;
  const int tid = threadIdx.x;

  if (blockIdx.x == 0 && blockIdx.y == 0 && tid < ZERO_WORDS)
    zero_tail[tid] = 0u;

  f4 g[MG]; float ga[MG];
#pragma unroll
  for (int j = 0; j < MG; j++) {
    g[j] = gt_boxes[b * MN + mbase + j];
    ga[j] = (g[j].z - g[j].x) * (g[j].w - g[j].y);
  }

  u64 best[MG];
#pragma unroll
  for (int j = 0; j < MG; j++) best[j] = 0ull;

  for (int p = tid; p < PN; p += 256) {
    f4 pr = priors[p];
    float px0 = pr.x - pr.z * 0.5f;
    float py0 = pr.y - pr.w * 0.5f;
    float px1 = pr.x + pr.z * 0.5f;
    float py1 = pr.y + pr.w * 0.5f;
    float pa  = (px1 - px0) * (py1 - py0);
    u32 key = 0xFFFFFFFFu - (u32)p;  // larger key = smaller p -> first-occurrence ties
#pragma unroll
    for (int j = 0; j < MG; j++) {
      float iw = fmaxf(fminf(px1, g[j].z) - fmaxf(px0, g[j].x), 0.0f);
      float ih = fmaxf(fminf(py1, g[j].w) - fmaxf(py0, g[j].y), 0.0f);
      float inter = iw * ih;
      float iou = inter / (pa + ga[j] - inter);
      u64 pk = ((u64)__float_as_uint(iou) << 32) | key;
      if (pk > best[j]) best[j] = pk;
    }
  }

  __shared__ u64 wred[4][MG];
  const int lane = tid & 63, wv = tid >> 6;
#pragma unroll
  for (int j = 0; j < MG; j++) {
    u64 v = best[j];
#pragma unroll
    for (int off = 1; off < 64; off <<= 1) {
      u64 o = shfl_xor_u64w(v, off, 64);
      if (o > v) v = o;
    }
    if (lane == 0) wred[wv][j] = v;
  }
  __syncthreads();
  if (tid < MG) {
    u64 v = wred[0][tid];
#pragma unroll
    for (int w = 1; w < 4; w++) { u64 o = wred[w][tid]; if (o > v) v = o; }
    packed_best[b * MN + mbase + tid] = v;
  }
}

// ---------------- K2: fused match + loss + per-batch inline top-k ----------
// k_big (TR=64 persistent baseline) with k_topk fused via per-batch
// completion counters: each WG, after its 16 tiles, threadfence +
// atomicAdd(done[b]); the 24th finisher runs batch b's top-k inline using
// an LDS histogram unioned over sconf (16 lane-indexed copies, 16.4 KB).
// Batch top-ks overlap other batches' main-phase work; no kernel boundary,
// no grid-wide barrier, no spin-waits.
__global__ __launch_bounds__(BLK)
void k_fused(const f4* __restrict__ loc_preds,
             const float* __restrict__ conf_preds,
             const f4* __restrict__ priors,
             const f4* __restrict__ gt_boxes,
             const int* __restrict__ gt_labels,
             const u64* __restrict__ packed,
             float* __restrict__ ce_neg,
             int* __restrict__ pos_cnt,
             int* __restrict__ num_pos,
             double* __restrict__ acc,
             u32* __restrict__ ticket,
             u32* __restrict__ done,
             float* __restrict__ out)
{
  const int wg = blockIdx.x;                // 0..WGS-1
  const int b = wg / WPB;
  const int tix0 = (wg % WPB) * TPW;        // first tile (of 384) in batch b
  const int t = threadIdx.x;
  const int q = t & 3, r = t >> 2;

  __shared__ union {
    float sconf[TR * CN];                   // 20,736 B (main phase)
    u32 hist[16][257];                      // 16,448 B (top-k phase)
  } u;
  __shared__ f4 sgt[MN]; __shared__ float sga[MN];
  __shared__ int slab[MN]; __shared__ u32 spidx[MN];
  __shared__ double ssl[4], sce[4]; __shared__ int spc[4];
  __shared__ int sh_last;
  __shared__ u32 cnt[256];
  __shared__ u32 sh_prefix; __shared__ int sh_rem; __shared__ int sh_k;

  if (t < MN) {
    f4 g = gt_boxes[b * MN + t];
    sgt[t] = g;
    sga[t] = (g.z - g.x) * (g.w - g.y);
    slab[t] = gt_labels[b * MN + t];
    spidx[t] = 0xFFFFFFFFu - (u32)(packed[b * MN + t] & 0xFFFFFFFFull);
  }

  const f4* gbase4 = (const f4*)(conf_preds + (size_t)b * PN * (size_t)CN);

  double a_sl1 = 0.0, a_cep = 0.0; int a_pos = 0;

  // prologue: load tile 0 into registers (tix0 is always a full tile)
  f4 tmp[6];
  {
    const f4* g4 = gbase4 + (size_t)tix0 * NF4_FULL;
#pragma unroll
    for (int j = 0; j < 5; j++) tmp[j] = g4[t + (j << 8)];
    if (t < 16) tmp[5] = g4[t + 1280];
  }

  for (int it = 0; it < TPW; ++it) {
    const int tix = tix0 + it;
    const int p0 = tix * TR;
    const int rows_here = (PN - p0 < TR) ? (PN - p0) : TR;
    const bool fullc = (rows_here == TR);

    __syncthreads();                        // prev compute done (LDS free)
    {
      f4* s4 = (f4*)u.sconf;
      if (fullc) {
#pragma unroll
        for (int j = 0; j < 5; j++) s4[t + (j << 8)] = tmp[j];
        if (t < 16) s4[t + 1280] = tmp[5];
      } else {
        const int nf4c = (rows_here * CN) >> 2;
#pragma unroll
        for (int j = 0; j < 6; j++) {
          const int i4 = t + (j << 8);
          if (i4 < nf4c) s4[i4] = tmp[j];
        }
      }
    }
    __syncthreads();                        // sconf ready

    if (it + 1 < TPW) {                     // issue next tile's loads
      const int tixn = tix + 1;
      const int rn = (PN - tixn * TR < TR) ? (PN - tixn * TR) : TR;
      const f4* g4 = gbase4 + (size_t)tixn * NF4_FULL;
      if (rn == TR) {
#pragma unroll
        for (int j = 0; j < 5; j++) tmp[j] = g4[t + (j << 8)];
        if (t < 16) tmp[5] = g4[t + 1280];
      } else {
        const int nf4n = (rn * CN) >> 2;
#pragma unroll
        for (int j = 0; j < 6; j++) {
          const int i4 = t + (j << 8);
          if (i4 < nf4n) tmp[j] = g4[i4];
        }
      }
    }

    if (r < rows_here) {
      const int p = p0 + r;
      const float* row = &u.sconf[r * CN];
      const int st = q * 20 + (q > 0);      // q0: 21 elems [0..20]; q1-3: 20 each
      float s0 = 0.f, s1 = 0.f, s2 = 0.f, s3 = 0.f;
#pragma unroll
      for (int j = 0; j < 20; j += 4) {
        s0 += __expf(row[st + j]);
        s1 += __expf(row[st + j + 1]);
        s2 += __expf(row[st + j + 2]);
        s3 += __expf(row[st + j + 3]);
      }
      float s = (s0 + s1) + (s2 + s3);
      if (q == 0) s += __expf(row[20]);
      s += __shfl_xor(s, 1, 4);
      s += __shfl_xor(s, 2, 4);

      // ---- matching: 8 IoUs per thread, f32 compare + index ----
      const f4 pr = priors[p];
      const float px0 = pr.x - pr.z * 0.5f, py0 = pr.y - pr.w * 0.5f;
      const float px1 = pr.x + pr.z * 0.5f, py1 = pr.y + pr.w * 0.5f;
      const float pa  = (px1 - px0) * (py1 - py0);
      float bv = -1.0f; int bi = 0; int ov = -1;
#pragma unroll
      for (int j = 0; j < 8; j++) {
        const int m = q * 8 + j;
        f4 g = sgt[m];
        float iw = fmaxf(fminf(px1, g.z) - fmaxf(px0, g.x), 0.0f);
        float ih = fmaxf(fminf(py1, g.w) - fmaxf(py0, g.y), 0.0f);
        float inter = iw * ih;
        float iou = inter / (pa + sga[m] - inter);
        if (iou > bv) { bv = iou; bi = m; }  // strict > ascending m = first-occurrence
        if (spidx[m] == (u32)p) ov = m;      // ascending m -> last-wins via max
      }
#pragma unroll
      for (int d = 1; d < 4; d <<= 1) {
        float bv2 = __shfl_xor(bv, d, 4);
        int   bi2 = __shfl_xor(bi, d, 4);
        int   ov2 = __shfl_xor(ov, d, 4);
        if (bv2 > bv || (bv2 == bv && bi2 < bi)) { bv = bv2; bi = bi2; }
        ov = max(ov, ov2);
      }

      int gi; bool pos;
      if (ov >= 0) { gi = ov; pos = true; }
      else         { gi = bi; pos = bv > 0.5f; }

      if (q == 0) {
        const int cls = pos ? slab[gi] : 0;
        const float xt = row[cls];
        float ce = fmaxf(logf(s) - xt, 0.0f);   // sign-free bits for radix select
        const size_t rp = (size_t)b * PN + p;
        if (pos) {
          a_cep += (double)ce; a_pos += 1;
          ce_neg[rp] = 0.0f;
          f4 g = sgt[gi];
          float gx = (g.x + g.z) * 0.5f, gy = (g.y + g.w) * 0.5f;
          float gw = g.z - g.x, gh = g.w - g.y;
          f4 lp = loc_preds[rp];
          float d0 = lp.x - (gx - pr.x) / pr.z;
          float d1 = lp.y - (gy - pr.y) / pr.w;
          float d2 = lp.z - logf(gw / pr.z);
          float d3 = lp.w - logf(gh / pr.w);
          a_sl1 += (double)(sl1f(d0) + sl1f(d1) + sl1f(d2) + sl1f(d3));
        } else {
          ce_neg[rp] = ce;
        }
      }
    }
  }

  // ---- per-WG epilogue: block reduce -> atomics -> done counter ----
  double dsl = a_sl1, dce = a_cep;
  int pc = a_pos;
#pragma unroll
  for (int off = 1; off < 64; off <<= 1) {
    dsl += __shfl_xor(dsl, off, 64);
    dce += __shfl_xor(dce, off, 64);
    pc  += __shfl_xor(pc, off, 64);
  }
  const int wv = t >> 6;
  if ((t & 63) == 0) { ssl[wv] = dsl; sce[wv] = dce; spc[wv] = pc; }
  __syncthreads();
  if (t == 0) {
    double a = ssl[0] + ssl[1] + ssl[2] + ssl[3];
    double c = sce[0] + sce[1] + sce[2] + sce[3];
    int qq = spc[0] + spc[1] + spc[2] + spc[3];
    if (qq) {
      atomicAdd(&acc[0], a);
      atomicAdd(&acc[1], c);
      atomicAdd(num_pos, qq);
      atomicAdd(&pos_cnt[b], qq);
    }
    __threadfence();                        // ce rows + counters visible device-wide
    const u32 old = atomicAdd(&done[b], 1u);
    sh_last = (old == WPB - 1) ? 1 : 0;
  }
  __syncthreads();
  if (!sh_last) return;

  // =============== inline top-k for batch b (last WG only) ================
  __threadfence();                          // acquire other WGs' ce writes
  if (t == 0) {
    int k = atomicAdd(&pos_cnt[b], 0) * 3;
    if (k < 1) k = 1;
    if (k > PN) k = PN;
    sh_k = k;
  }
  __syncthreads();

  const float* rowp = ce_neg + (size_t)b * PN;
  const int hc = t & 15;                    // histogram copy (16 lane-spread copies)

  u32 prefix = 0; int rem = sh_k;
  for (int shift = 24; shift >= 0; shift -= 8) {
    for (int i = t; i < 16 * 257; i += BLK) ((u32*)u.hist)[i] = 0u;
    __syncthreads();
    const u32 pmask = (shift == 24) ? 0u : (0xFFFFFFFFu << (shift + 8));
    for (int p = t; p < PN; p += BLK) {
      u32 uu = __float_as_uint(rowp[p]);
      if ((uu & pmask) == (prefix & pmask))
        atomicAdd(&u.hist[hc][(uu >> shift) & 255], 1u);
    }
    __syncthreads();
    {
      u32 c = 0;
#pragma unroll
      for (int w = 0; w < 16; w++) c += u.hist[w][t];
      cnt[t] = c;
    }
    __syncthreads();
    // parallel suffix scan: cnt[d] <- sum_{d'>=d} count[d']
#pragma unroll
    for (int off = 1; off < 256; off <<= 1) {
      u32 o = (t + off < 256) ? cnt[t + off] : 0u;
      __syncthreads();
      cnt[t] += o;
      __syncthreads();
    }
    // unique crossing: largest d with S[d] >= rem (exists: S[0] >= rem)
    {
      const u32 Sd  = cnt[t];
      const u32 Sd1 = (t == 255) ? 0u : cnt[t + 1];
      if ((int)Sd >= rem && (int)Sd1 < rem) {
        sh_prefix = prefix | ((u32)t << shift);
        sh_rem = rem - (int)Sd1;
      }
    }
    __syncthreads();
    prefix = sh_prefix; rem = sh_rem;
    __syncthreads();
  }

  const float vstar = __uint_as_float(prefix);
  double sg = 0.0;
  for (int p = t; p < PN; p += BLK) {
    float v = rowp[p];
    if (__float_as_uint(v) > prefix) sg += (double)v;
  }
#pragma unroll
  for (int off = 1; off < 64; off <<= 1) sg += __shfl_xor(sg, off, 64);
  if ((t & 63) == 0) ssl[wv] = sg;          // reuse ssl as reduce scratch
  __syncthreads();
  if (t == 0) {
    double tacc = ssl[0] + ssl[1] + ssl[2] + ssl[3];
    tacc += (double)rem * (double)vstar;    // ties at v* contribute identically
    atomicAdd(&acc[2], tacc);
    __threadfence();
    const u32 old = atomicAdd(ticket, 1u);
    if (old == BN - 1) {                    // last batch finalizes (atomic reads)
      double a0 = atomicAdd(&acc[0], 0.0);
      double a1 = atomicAdd(&acc[1], 0.0);
      double a2 = atomicAdd(&acc[2], 0.0);
      int np = atomicAdd(num_pos, 0);
      if (np < 1) np = 1;
      out[0] = (float)((a0 + a1 + a2) / (double)np);
    }
  }
}

extern "C" void kernel_launch(void* const* d_in, const int* in_sizes, int n_in,
                              void* d_out, int out_size, void* d_ws, size_t ws_size,
                              hipStream_t stream)
{
  const f4*    loc    = (const f4*)d_in[0];
  const float* conf   = (const float*)d_in[1];
  const f4*    priors = (const f4*)d_in[2];
  const f4*    gt     = (const f4*)d_in[3];
  const int*   labels = (const int*)d_in[4];

  char* ws = (char*)d_ws;
  float* ce_neg   = (float*)(ws);
  u64*   packed   = (u64*)(ws + OFF_PACK);
  int*   pos_cnt  = (int*)(ws + OFF_PCNT);
  int*   num_pos  = (int*)(ws + OFF_NP);
  double* acc     = (double*)(ws + OFF_ACC);
  u32*   ticket   = (u32*)(ws + OFF_TICK);
  u32*   done     = (u32*)(ws + OFF_DONE);

  k_gt_best<<<dim3(MN / MG, BN), 256, 0, stream>>>(priors, gt, packed,
                                                   (u32*)(ws + ZERO_OFF));
  k_fused<<<WGS, BLK, 0, stream>>>(loc, conf, priors, gt, labels,
                                   packed, ce_neg,
                                   pos_cnt, num_pos, acc, ticket, done,
                                   (float*)d_out);
}

// Round 23
// 234.050 us; speedup vs baseline: 1.9085x; 1.9085x over previous
//
#include <hip/hip_runtime.h>
#include <stdint.h>

#define PN 24564
#define BN 64
#define MN 32
#define CN 81
#define MG 4       // gt boxes per block in k_gt_best
#define TR 64      // rows per tile in k_big (measured optimum)
#define TPW 16     // tiles per workgroup (persistent)
#define WPB 24     // workgroups per batch (384 tiles / 16)
#define WGS (BN * WPB)   // 1536 persistent workgroups

typedef float f4 __attribute__((ext_vector_type(4)));
typedef unsigned long long u64;
typedef unsigned int u32;

// ---------------- workspace layout ----------------
constexpr size_t SZ_BP4   = (size_t)BN * PN * 4;        // ce_neg
constexpr size_t OFF_PACK = SZ_BP4;                     // packed u64 [BN*MN]
constexpr size_t SZ_PACK  = (size_t)BN * MN * 8;
constexpr size_t OFF_PCNT = OFF_PACK + SZ_PACK;         // per-batch pos count (BN i32)
constexpr size_t OFF_NP   = OFF_PCNT + BN * 4;          // global num_pos
constexpr size_t OFF_ACC  = OFF_NP + 8;                 // 3 doubles
constexpr size_t OFF_TICK = OFF_ACC + 24;               // ticket u32
constexpr size_t ZERO_OFF = OFF_PCNT;
constexpr size_t ZERO_WORDS = (BN * 4 + 8 + 24 + 4) / 4;  // 73 u32 words

__device__ __forceinline__ float sl1f(float d) {
  float ad = fabsf(d);
  return ad < 1.0f ? 0.5f * d * d : ad - 0.5f;
}

__device__ __forceinline__ u64 shfl_xor_u64w(u64 v, int m, int w) {
  u32 lo = (u32)v, hi = (u32)(v >> 32);
  lo = (u32)__shfl_xor((int)lo, m, w);
  hi = (u32)__shfl_xor((int)hi, m, w);
  return ((u64)hi << 32) | lo;
}

// ---------------- K1: per-gt best prior (argmax over p), 4 gt per block ----
// Block (0,0) also zeroes the accumulator tail + ticket.
__global__ __launch_bounds__(256)
void k_gt_best(const f4* __restrict__ priors,
               const f4* __restrict__ gt_boxes,
               u64* __restrict__ packed_best,
               u32* __restrict__ zero_tail)
{
  const int b = blockIdx.y;
  const int mbase = blockIdx.x * MG;
  const int tid = threadIdx.x;

  if (blockIdx.x == 0 && blockIdx.y == 0 && tid < ZERO_WORDS)
    zero_tail[tid] = 0u;

  f4 g[MG]; float ga[MG];
#pragma unroll
  for (int j = 0; j < MG; j++) {
    g[j] = gt_boxes[b * MN + mbase + j];
    ga[j] = (g[j].z - g[j].x) * (g[j].w - g[j].y);
  }

  u64 best[MG];
#pragma unroll
  for (int j = 0; j < MG; j++) best[j] = 0ull;

  for (int p = tid; p < PN; p += 256) {
    f4 pr = priors[p];
    float px0 = pr.x - pr.z * 0.5f;
    float py0 = pr.y - pr.w * 0.5f;
    float px1 = pr.x + pr.z * 0.5f;
    float py1 = pr.y + pr.w * 0.5f;
    float pa  = (px1 - px0) * (py1 - py0);
    u32 key = 0xFFFFFFFFu - (u32)p;  // larger key = smaller p -> first-occurrence ties
#pragma unroll
    for (int j = 0; j < MG; j++) {
      float iw = fmaxf(fminf(px1, g[j].z) - fmaxf(px0, g[j].x), 0.0f);
      float ih = fmaxf(fminf(py1, g[j].w) - fmaxf(py0, g[j].y), 0.0f);
      float inter = iw * ih;
      float iou = inter / (pa + ga[j] - inter);
      u64 pk = ((u64)__float_as_uint(iou) << 32) | key;
      if (pk > best[j]) best[j] = pk;
    }
  }

  __shared__ u64 wred[4][MG];
  const int lane = tid & 63, wv = tid >> 6;
#pragma unroll
  for (int j = 0; j < MG; j++) {
    u64 v = best[j];
#pragma unroll
    for (int off = 1; off < 64; off <<= 1) {
      u64 o = shfl_xor_u64w(v, off, 64);
      if (o > v) v = o;
    }
    if (lane == 0) wred[wv][j] = v;
  }
  __syncthreads();
  if (tid < MG) {
    u64 v = wred[0][tid];
#pragma unroll
    for (int w = 1; w < 4; w++) { u64 o = wred[w][tid]; if (o > v) v = o; }
    packed_best[b * MN + mbase + tid] = v;
  }
}

// ---------------- K2: fused match + loc loss + CE (PERSISTENT WGs) ---------
__global__ __launch_bounds__(256)
void k_big(const f4* __restrict__ loc_preds,
           const float* __restrict__ conf_preds,
           const f4* __restrict__ priors,
           const f4* __restrict__ gt_boxes,
           const int* __restrict__ gt_labels,
           const u64* __restrict__ packed,
           float* __restrict__ ce_neg,
           int* __restrict__ pos_cnt,
           int* __restrict__ num_pos,
           double* __restrict__ acc)
{
  const int wg = blockIdx.x;                // 0..WGS-1
  const int b = wg / WPB;
  const int tix0 = (wg % WPB) * TPW;        // first tile (of 384) in batch b
  const int t = threadIdx.x;
  const int q = t & 3, r = t >> 2;

  __shared__ float sconf[TR * CN];          // 20,736 B (single buffer, reused)
  __shared__ f4 sgt[MN]; __shared__ float sga[MN];
  __shared__ int slab[MN]; __shared__ u32 spidx[MN];
  __shared__ double ssl[4], sce[4]; __shared__ int spc[4];

  if (t < MN) {
    f4 g = gt_boxes[b * MN + t];
    sgt[t] = g;
    sga[t] = (g.z - g.x) * (g.w - g.y);
    slab[t] = gt_labels[b * MN + t];
    spidx[t] = 0xFFFFFFFFu - (u32)(packed[b * MN + t] & 0xFFFFFFFFull);
  }

  const f4* gbase4 = (const f4*)(conf_preds + (size_t)b * PN * (size_t)CN);

  double a_sl1 = 0.0, a_cep = 0.0; int a_pos = 0;

  // prologue: load tile 0 into registers
  f4 tmp[6];
  {
    const int p0 = tix0 * TR;
    const int rows0 = (PN - p0 < TR) ? (PN - p0) : TR;
    const int nf4 = (rows0 * CN) >> 2;
    const f4* g4 = gbase4 + (size_t)tix0 * (TR * CN / 4);
#pragma unroll
    for (int j = 0; j < 6; j++) {
      const int i4 = t + (j << 8);
      if (i4 < nf4) tmp[j] = g4[i4];
    }
  }

  for (int it = 0; it < TPW; ++it) {
    const int tix = tix0 + it;
    const int p0 = tix * TR;
    const int rows_here = (PN - p0 < TR) ? (PN - p0) : TR;
    const int nf4c = (rows_here * CN) >> 2;

    __syncthreads();                        // prev compute done (LDS free)
    {
      f4* s4 = (f4*)sconf;
#pragma unroll
      for (int j = 0; j < 6; j++) {
        const int i4 = t + (j << 8);
        if (i4 < nf4c) s4[i4] = tmp[j];
      }
    }
    __syncthreads();                        // sconf ready

    if (it + 1 < TPW) {                     // issue next tile's loads
      const int tixn = tix + 1;
      const int p0n = tixn * TR;
      const int rn = (PN - p0n < TR) ? (PN - p0n) : TR;
      const int nf4n = (rn * CN) >> 2;
      const f4* g4 = gbase4 + (size_t)tixn * (TR * CN / 4);
#pragma unroll
      for (int j = 0; j < 6; j++) {
        const int i4 = t + (j << 8);
        if (i4 < nf4n) tmp[j] = g4[i4];
      }
    }

    if (r < rows_here) {
      const int p = p0 + r;
      const float* row = &sconf[r * CN];
      const int st = q * 20 + (q > 0);      // 0,21,41,61 ; counts 21,20,20,20
      float e[21];
      float mx = -3.0e38f;
#pragma unroll
      for (int j = 0; j < 21; j++) {
        const bool ok = (q == 0) | (j < 20);
        e[j] = ok ? row[st + j] : -3.0e38f;
        mx = fmaxf(mx, e[j]);
      }
      mx = fmaxf(mx, __shfl_xor(mx, 1, 4));
      mx = fmaxf(mx, __shfl_xor(mx, 2, 4));
      float s = 0.f;
#pragma unroll
      for (int j = 0; j < 21; j++) s += __expf(e[j] - mx);
      s += __shfl_xor(s, 1, 4);
      s += __shfl_xor(s, 2, 4);

      // ---- matching: 8 IoUs per thread ----
      const f4 pr = priors[p];
      const float px0 = pr.x - pr.z * 0.5f, py0 = pr.y - pr.w * 0.5f;
      const float px1 = pr.x + pr.z * 0.5f, py1 = pr.y + pr.w * 0.5f;
      const float pa  = (px1 - px0) * (py1 - py0);
      u64 bk = 0ull;
      int ov = -1;
#pragma unroll
      for (int j = 0; j < 8; j++) {
        const int m = q * 8 + j;
        f4 g = sgt[m];
        float iw = fmaxf(fminf(px1, g.z) - fmaxf(px0, g.x), 0.0f);
        float ih = fmaxf(fminf(py1, g.w) - fmaxf(py0, g.y), 0.0f);
        float inter = iw * ih;
        float iou = inter / (pa + sga[m] - inter);
        u64 key = ((u64)__float_as_uint(iou) << 32) | (u32)(MN - 1 - m);
        if (key > bk) bk = key;             // ties -> smaller m (first occurrence)
        if (spidx[m] == (u32)p) ov = m;     // ascending m -> last-wins
      }
      { u64 o = shfl_xor_u64w(bk, 1, 4); if (o > bk) bk = o;
        o = shfl_xor_u64w(bk, 2, 4); if (o > bk) bk = o; }
      ov = max(ov, __shfl_xor(ov, 1, 4));
      ov = max(ov, __shfl_xor(ov, 2, 4));

      int gi; bool pos;
      if (ov >= 0) { gi = ov; pos = true; }
      else {
        gi = MN - 1 - (int)(bk & 31ull);
        pos = __uint_as_float((u32)(bk >> 32)) > 0.5f;
      }

      if (q == 0) {
        const int cls = pos ? slab[gi] : 0;
        const float xt = row[cls];
        float ce = fmaxf(mx + logf(s) - xt, 0.0f);  // sign-free bits for radix select
        const size_t rp = (size_t)b * PN + p;
        if (pos) {
          a_cep += (double)ce; a_pos += 1;
          ce_neg[rp] = 0.0f;
          f4 g = sgt[gi];
          float gx = (g.x + g.z) * 0.5f, gy = (g.y + g.w) * 0.5f;
          float gw = g.z - g.x, gh = g.w - g.y;
          f4 lp = loc_preds[rp];
          float d0 = lp.x - (gx - pr.x) / pr.z;
          float d1 = lp.y - (gy - pr.y) / pr.w;
          float d2 = lp.z - logf(gw / pr.z);
          float d3 = lp.w - logf(gh / pr.w);
          a_sl1 += (double)(sl1f(d0) + sl1f(d1) + sl1f(d2) + sl1f(d3));
        } else {
          ce_neg[rp] = ce;
        }
      }
    }
  }

  // ---- once per WG: block reduce -> atomics ----
  double dsl = a_sl1, dce = a_cep;
  int pc = a_pos;
#pragma unroll
  for (int off = 1; off < 64; off <<= 1) {
    dsl += __shfl_xor(dsl, off, 64);
    dce += __shfl_xor(dce, off, 64);
    pc  += __shfl_xor(pc, off, 64);
  }
  const int wv = t >> 6;
  if ((t & 63) == 0) { ssl[wv] = dsl; sce[wv] = dce; spc[wv] = pc; }
  __syncthreads();
  if (t == 0) {
    double a = ssl[0] + ssl[1] + ssl[2] + ssl[3];
    double c = sce[0] + sce[1] + sce[2] + sce[3];
    int qq = spc[0] + spc[1] + spc[2] + spc[3];
    if (qq) {
      atomicAdd(&acc[0], a);
      atomicAdd(&acc[1], c);
      atomicAdd(num_pos, qq);
      atomicAdd(&pos_cnt[b], qq);
    }
  }
}

// ---------------- K3: per-batch exact top-k sum via radix select ------------
// Per-LANE histogram copies (conflict-free); ticket-finalize replaces k_final.
__global__ __launch_bounds__(1024)
void k_topk(const float* __restrict__ ce_neg,
            const int* __restrict__ pos_cnt,
            double* __restrict__ acc,
            int* __restrict__ num_pos,
            u32* __restrict__ ticket,
            float* __restrict__ out)
{
  const int b = blockIdx.x;
  const float* row = ce_neg + (size_t)b * PN;
  int k = pos_cnt[b] * 3;
  if (k < 1) k = 1;
  if (k > PN) k = PN;

  const int tid = threadIdx.x;
  const int lane = tid & 63;
  const int wv = tid >> 6;

  __shared__ u32 hist[64][257];             // 65,792 B; copy = lane
  __shared__ u32 cnt[256];
  __shared__ u32 sh_prefix; __shared__ int sh_rem;

  u32 prefix = 0; int rem = k;
  for (int shift = 24; shift >= 0; shift -= 8) {
    for (int i = tid; i < 64 * 257; i += 1024) ((u32*)hist)[i] = 0u;
    __syncthreads();
    const u32 pmask = (shift == 24) ? 0u : (0xFFFFFFFFu << (shift + 8));
    for (int p = tid; p < PN; p += 1024) {
      u32 u = __float_as_uint(row[p]);
      if ((u & pmask) == (prefix & pmask))
        atomicAdd(&hist[lane][(u >> shift) & 255], 1u);
    }
    __syncthreads();
    if (tid < 256) {
      u32 c = 0;
#pragma unroll
      for (int l = 0; l < 64; l++) c += hist[l][tid];
      cnt[tid] = c;
    }
    __syncthreads();
    // parallel suffix scan: cnt[d] <- sum_{d'>=d} count[d']
#pragma unroll
    for (int off = 1; off < 256; off <<= 1) {
      u32 o = 0;
      if (tid < 256 && tid + off < 256) o = cnt[tid + off];
      __syncthreads();
      if (tid < 256) cnt[tid] += o;
      __syncthreads();
    }
    // unique crossing: largest d with S[d] >= rem (exists: S[0] >= rem)
    if (tid < 256) {
      const u32 Sd  = cnt[tid];
      const u32 Sd1 = (tid == 255) ? 0u : cnt[tid + 1];
      if ((int)Sd >= rem && (int)Sd1 < rem) {
        sh_prefix = prefix | ((u32)tid << shift);
        sh_rem = rem - (int)Sd1;
      }
    }
    __syncthreads();
    prefix = sh_prefix; rem = sh_rem;
    __syncthreads();
  }

  const float vstar = __uint_as_float(prefix);
  double sg = 0.0;
  for (int p = tid; p < PN; p += 1024) {
    float v = row[p];
    if (__float_as_uint(v) > prefix) sg += (double)v;
  }
#pragma unroll
  for (int off = 1; off < 64; off <<= 1) sg += __shfl_xor(sg, off, 64);
  __shared__ double sred[16];
  if (lane == 0) sred[wv] = sg;
  __syncthreads();
  if (tid == 0) {
    double tacc = 0.0;
    for (int w = 0; w < 16; w++) tacc += sred[w];
    tacc += (double)rem * (double)vstar;   // ties at v* contribute identically
    atomicAdd(&acc[2], tacc);
    __threadfence();
    const u32 old = atomicAdd(ticket, 1u);
    if (old == BN - 1) {                   // last WG finalizes (atomic reads)
      double a0 = atomicAdd(&acc[0], 0.0);
      double a1 = atomicAdd(&acc[1], 0.0);
      double a2 = atomicAdd(&acc[2], 0.0);
      int np = atomicAdd(num_pos, 0);
      if (np < 1) np = 1;
      out[0] = (float)((a0 + a1 + a2) / (double)np);
    }
  }
}

extern "C" void kernel_launch(void* const* d_in, const int* in_sizes, int n_in,
                              void* d_out, int out_size, void* d_ws, size_t ws_size,
                              hipStream_t stream)
{
  const f4*    loc    = (const f4*)d_in[0];
  const float* conf   = (const float*)d_in[1];
  const f4*    priors = (const f4*)d_in[2];
  const f4*    gt     = (const f4*)d_in[3];
  const int*   labels = (const int*)d_in[4];

  char* ws = (char*)d_ws;
  float* ce_neg   = (float*)(ws);
  u64*   packed   = (u64*)(ws + OFF_PACK);
  int*   pos_cnt  = (int*)(ws + OFF_PCNT);
  int*   num_pos  = (int*)(ws + OFF_NP);
  double* acc     = (double*)(ws + OFF_ACC);
  u32*   ticket   = (u32*)(ws + OFF_TICK);

  k_gt_best<<<dim3(MN / MG, BN), 256, 0, stream>>>(priors, gt, packed,
                                                   (u32*)(ws + ZERO_OFF));
  k_big<<<WGS, 256, 0, stream>>>(loc, conf, priors, gt, labels,
                                 packed, ce_neg,
                                 pos_cnt, num_pos, acc);
  k_topk<<<BN, 1024, 0, stream>>>(ce_neg, pos_cnt, acc, num_pos, ticket,
                                  (float*)d_out);
}